// Round 1
// baseline (86.749 us; speedup 1.0000x reference)
//
#include <hip/hip_runtime.h>
#include <math.h>

#define NBOX 16
#define GX 64
#define GY 64
#define GZ 8
#define NVOX (GX * GY * GZ)   // 32768
#define BLOCKS_PER_BATCH (NVOX / 256)  // 128

// One thread per voxel. Block = 256 threads; 128 blocks per batch; grid = 4*128.
__global__ __launch_bounds__(256) void box3d_encoder_kernel(
    const float* __restrict__ corners,   // (B, 16, 8, 3)
    const float* __restrict__ vsizes,    // (B, 3) -- reference uses row 0 only
    float* __restrict__ out)             // (B*NVOX, 2)
{
    // Per-box precomputed data in LDS
    __shared__ float s_px[NBOX][4], s_py[NBOX][4];
    __shared__ float s_zb0[NBOX], s_zb1[NBOX], s_qa[NBOX];
    __shared__ float s_sin[NBOX], s_cos[NBOX];
    __shared__ float s_ax0[NBOX], s_ax1[NBOX], s_ay0[NBOX], s_ay1[NBOX];

    const int b     = blockIdx.x >> 7;            // / BLOCKS_PER_BATCH
    const int vbase = (blockIdx.x & (BLOCKS_PER_BATCH - 1)) << 8;
    const int t     = threadIdx.x;

    const float vs0 = vsizes[0], vs1 = vsizes[1], vs2 = vsizes[2];
    const float vox_vol = vs0 * vs1 * vs2;

    if (t < NBOX) {
        const float* c8 = corners + ((size_t)b * NBOX + t) * 8 * 3;
        float px[4], py[4];
        float zmin = c8[2], zmax = c8[2];
        #pragma unroll
        for (int k = 0; k < 8; k++) {
            float z = c8[k * 3 + 2];
            zmin = fminf(zmin, z);
            zmax = fmaxf(zmax, z);
        }
        #pragma unroll
        for (int k = 0; k < 4; k++) { px[k] = c8[k * 3 + 0]; py[k] = c8[k * 3 + 1]; }

        // quad (shoelace) area of bottom face
        float sum = 0.0f;
        #pragma unroll
        for (int k = 0; k < 4; k++) {
            int n = (k + 1) & 3;
            sum += px[k] * py[n] - px[n] * py[k];
        }
        s_qa[t] = 0.5f * fabsf(sum);

        // heading encoding: atan2(y0-y3, x0-x3) -> (sin, cos)
        float h = atan2f(py[0] - py[3], px[0] - px[3]);
        s_sin[t] = sinf(h);
        s_cos[t] = cosf(h);

        s_zb0[t] = zmin;
        s_zb1[t] = zmax;

        float ax0 = px[0], ax1 = px[0], ay0 = py[0], ay1 = py[0];
        #pragma unroll
        for (int k = 1; k < 4; k++) {
            ax0 = fminf(ax0, px[k]); ax1 = fmaxf(ax1, px[k]);
            ay0 = fminf(ay0, py[k]); ay1 = fmaxf(ay1, py[k]);
        }
        s_ax0[t] = ax0; s_ax1[t] = ax1; s_ay0[t] = ay0; s_ay1[t] = ay1;

        #pragma unroll
        for (int k = 0; k < 4; k++) { s_px[t][k] = px[k]; s_py[t][k] = py[k]; }
    }
    __syncthreads();

    // voxel indices: v = i*512 + j*8 + k ; ii = i-32, jj = j-32, kk = k-4
    const int v  = vbase + t;
    const int iz = v & 7;
    const int iy = (v >> 3) & 63;
    const int ix = v >> 9;
    const float fi = (float)(ix - 32);
    const float fj = (float)(iy - 32);
    const float fk = (float)(iz - 4);
    const float x0 = fi * vs0, x1 = (fi + 1.0f) * vs0;
    const float y0 = fj * vs1, y1 = (fj + 1.0f) * vs1;
    const float z0 = fk * vs2, z1 = (fk + 1.0f) * vs2;

    float best_iou   = -1.0f;
    float best_inter = 0.0f;
    int   best_idx   = 0;

    for (int n = 0; n < NBOX; n++) {
        float iou = 0.0f, inter = 0.0f;

        const float zb0 = s_zb0[n], zb1 = s_zb1[n];
        const float zov = fminf(z1, zb1) - fmaxf(z0, zb0);
        const bool overlap = (zov > 0.0f)
                          && (s_ax0[n] < x1) && (s_ax1[n] > x0)
                          && (s_ay0[n] < y1) && (s_ay1[n] > y0);
        if (overlap) {
            // Sutherland-Hodgman clip of convex quad against the rect.
            // Plane k: d(x,y) = a*x + b*y + c, keep d >= 0.
            float vx[8], vy[8], tx[8], ty[8];
            int cnt = 4;
            #pragma unroll
            for (int k = 0; k < 4; k++) { vx[k] = s_px[n][k]; vy[k] = s_py[n][k]; }

            const float pa[4] = { 1.0f, -1.0f, 0.0f,  0.0f};
            const float pb[4] = { 0.0f,  0.0f, 1.0f, -1.0f};
            const float pc[4] = { -x0,    x1,  -y0,    y1};

            for (int p = 0; p < 4; p++) {
                const float a = pa[p], bb = pb[p], c = pc[p];
                int oc = 0;
                for (int e = 0; e < cnt; e++) {
                    const int ne = (e + 1 < cnt) ? e + 1 : 0;
                    const float cx = vx[e],  cy = vy[e];
                    const float nx = vx[ne], ny = vy[ne];
                    const float dc = a * cx + bb * cy + c;
                    const float dn = a * nx + bb * ny + c;
                    if ((dc >= 0.0f) != (dn >= 0.0f)) {
                        float denom = dc - dn;
                        denom = (fabsf(denom) < 1e-12f) ? 1.0f : denom;
                        const float tt = dc / denom;
                        if (oc < 8) { tx[oc] = cx + tt * (nx - cx); ty[oc] = cy + tt * (ny - cy); oc++; }
                    }
                    if (dn >= 0.0f) {
                        if (oc < 8) { tx[oc] = nx; ty[oc] = ny; oc++; }
                    }
                }
                cnt = oc;
                #pragma unroll
                for (int k = 0; k < 8; k++) { vx[k] = tx[k]; vy[k] = ty[k]; }
            }

            // shoelace area of clipped polygon
            float sum = 0.0f;
            for (int e = 0; e < cnt; e++) {
                const int ne = (e + 1 < cnt) ? e + 1 : 0;
                sum += vx[e] * vy[ne] - vx[ne] * vy[e];
            }
            const float area = 0.5f * fabsf(sum);

            inter = area * zov;
            const float box_vol = s_qa[n] * (zb1 - zb0);
            iou = inter / (vox_vol + box_vol - inter + 1e-9f);
        }

        if (iou > best_iou) {   // strict > => first-max, matches jnp.argmax
            best_iou   = iou;
            best_inter = inter;
            best_idx   = n;
        }
    }

    const bool mask = best_inter > 0.5f * vox_vol;
    const float o0 = mask ? s_sin[best_idx] : 0.0f;
    const float o1 = mask ? s_cos[best_idx] : 0.0f;

    const size_t oidx = ((size_t)b * NVOX + v) * 2;
    out[oidx]     = o0;
    out[oidx + 1] = o1;
}

extern "C" void kernel_launch(void* const* d_in, const int* in_sizes, int n_in,
                              void* d_out, int out_size, void* d_ws, size_t ws_size,
                              hipStream_t stream) {
    const float* corners = (const float*)d_in[0];   // (4,16,8,3) fp32
    const float* vsizes  = (const float*)d_in[1];   // (4,3) fp32
    float* out = (float*)d_out;                     // (4*32768, 2) fp32

    const int B = 4;
    dim3 grid(B * BLOCKS_PER_BATCH);  // 512 blocks
    dim3 block(256);
    box3d_encoder_kernel<<<grid, block, 0, stream>>>(corners, vsizes, out);
}

// Round 2
// 85.866 us; speedup vs baseline: 1.0103x; 1.0103x over previous
//
#include <hip/hip_runtime.h>
#include <math.h>

#define NBOX 16
#define GX 64
#define GY 64
#define GZ 8
#define NVOX (GX * GY * GZ)   // 32768
#define BLOCKS_PER_BATCH (NVOX / 256)  // 128

// Branch-free Sutherland-Hodgman clip stage. All array indices are
// compile-time constants after unrolling, so vx/vy/tx/ty live entirely in
// VGPRs (no scratch). The dynamic append tx[oc]=v becomes an unrolled
// select-write over OUTMAX slots (v_cndmask chains).
// Emission order per edge: intersection point first, then next-vertex --
// identical to the reference's stable argsort compaction.
template<int INMAX, int OUTMAX>
__device__ __forceinline__ int clip_stage(float a, float b, float c,
                                          const float* __restrict__ vx,
                                          const float* __restrict__ vy,
                                          float* __restrict__ tx,
                                          float* __restrict__ ty,
                                          int cnt)
{
    int oc = 0;
    #pragma unroll
    for (int e = 0; e < INMAX; e++) {
        const bool cvalid = (e < cnt);
        const bool wrap   = !(e + 1 < cnt);          // next index = 0 when wrapping
        const float cx = vx[e], cy = vy[e];
        const float nx = wrap ? vx[0] : vx[e + 1];   // both indices constant
        const float ny = wrap ? vy[0] : vy[e + 1];
        const float dc = a * cx + b * cy + c;
        const float dn = a * nx + b * ny + c;
        const bool cpos = (dc >= 0.0f);
        const bool npos = (dn >= 0.0f);
        float denom = dc - dn;
        denom = (fabsf(denom) < 1e-12f) ? 1.0f : denom;
        const float tt  = dc / denom;
        const float ipx = cx + tt * (nx - cx);
        const float ipy = cy + tt * (ny - cy);
        const bool emit_ip = cvalid && (cpos != npos);
        const bool emit_nx = cvalid && npos;
        #pragma unroll
        for (int k = 0; k < OUTMAX; k++) {
            const bool w = emit_ip && (oc == k);
            tx[k] = w ? ipx : tx[k];
            ty[k] = w ? ipy : ty[k];
        }
        oc += emit_ip ? 1 : 0;
        #pragma unroll
        for (int k = 0; k < OUTMAX; k++) {
            const bool w = emit_nx && (oc == k);
            tx[k] = w ? nx : tx[k];
            ty[k] = w ? ny : ty[k];
        }
        oc += emit_nx ? 1 : 0;
    }
    return oc;
}

// One thread per voxel. Block = 256 threads; 128 blocks per batch; grid = 4*128.
__global__ __launch_bounds__(256) void box3d_encoder_kernel(
    const float* __restrict__ corners,   // (B, 16, 8, 3)
    const float* __restrict__ vsizes,    // (B, 3) -- reference uses row 0 only
    float* __restrict__ out)             // (B*NVOX, 2)
{
    // Per-box precomputed data in LDS
    __shared__ float s_px[NBOX][4], s_py[NBOX][4];
    __shared__ float s_zb0[NBOX], s_zb1[NBOX], s_qa[NBOX];
    __shared__ float s_sin[NBOX], s_cos[NBOX];
    __shared__ float s_ax0[NBOX], s_ax1[NBOX], s_ay0[NBOX], s_ay1[NBOX];

    const int b     = blockIdx.x >> 7;            // / BLOCKS_PER_BATCH
    const int vbase = (blockIdx.x & (BLOCKS_PER_BATCH - 1)) << 8;
    const int t     = threadIdx.x;

    const float vs0 = vsizes[0], vs1 = vsizes[1], vs2 = vsizes[2];
    const float vox_vol = vs0 * vs1 * vs2;

    if (t < NBOX) {
        const float* c8 = corners + ((size_t)b * NBOX + t) * 8 * 3;
        float px[4], py[4];
        float zmin = c8[2], zmax = c8[2];
        #pragma unroll
        for (int k = 0; k < 8; k++) {
            float z = c8[k * 3 + 2];
            zmin = fminf(zmin, z);
            zmax = fmaxf(zmax, z);
        }
        #pragma unroll
        for (int k = 0; k < 4; k++) { px[k] = c8[k * 3 + 0]; py[k] = c8[k * 3 + 1]; }

        // quad (shoelace) area of bottom face
        float sum = 0.0f;
        #pragma unroll
        for (int k = 0; k < 4; k++) {
            int n = (k + 1) & 3;
            sum += px[k] * py[n] - px[n] * py[k];
        }
        s_qa[t] = 0.5f * fabsf(sum);

        // heading encoding: atan2(y0-y3, x0-x3) -> (sin, cos)
        float h = atan2f(py[0] - py[3], px[0] - px[3]);
        s_sin[t] = sinf(h);
        s_cos[t] = cosf(h);

        s_zb0[t] = zmin;
        s_zb1[t] = zmax;

        float ax0 = px[0], ax1 = px[0], ay0 = py[0], ay1 = py[0];
        #pragma unroll
        for (int k = 1; k < 4; k++) {
            ax0 = fminf(ax0, px[k]); ax1 = fmaxf(ax1, px[k]);
            ay0 = fminf(ay0, py[k]); ay1 = fmaxf(ay1, py[k]);
        }
        s_ax0[t] = ax0; s_ax1[t] = ax1; s_ay0[t] = ay0; s_ay1[t] = ay1;

        #pragma unroll
        for (int k = 0; k < 4; k++) { s_px[t][k] = px[k]; s_py[t][k] = py[k]; }
    }
    __syncthreads();

    // voxel indices: v = i*512 + j*8 + k ; ii = i-32, jj = j-32, kk = k-4
    const int v  = vbase + t;
    const int iz = v & 7;
    const int iy = (v >> 3) & 63;
    const int ix = v >> 9;
    const float fi = (float)(ix - 32);
    const float fj = (float)(iy - 32);
    const float fk = (float)(iz - 4);
    const float x0 = fi * vs0, x1 = (fi + 1.0f) * vs0;
    const float y0 = fj * vs1, y1 = (fj + 1.0f) * vs1;
    const float z0 = fk * vs2, z1 = (fk + 1.0f) * vs2;

    float best_iou   = -1.0f;
    float best_inter = 0.0f;
    int   best_idx   = 0;

    for (int n = 0; n < NBOX; n++) {
        float iou = 0.0f, inter = 0.0f;

        const float zb0 = s_zb0[n], zb1 = s_zb1[n];
        const float zov = fminf(z1, zb1) - fmaxf(z0, zb0);
        const bool overlap = (zov > 0.0f)
                          && (s_ax0[n] < x1) && (s_ax1[n] > x0)
                          && (s_ay0[n] < y1) && (s_ay1[n] > y0);
        if (overlap) {
            // Register-resident SH clip: quad vs axis-aligned rect.
            // Vertex counts per stage: 4 -> <=5 -> <=6 -> <=7 -> <=8.
            float ax[8], ay[8], bx[8], by[8];
            #pragma unroll
            for (int k = 0; k < 8; k++) { ax[k] = 0.0f; ay[k] = 0.0f; bx[k] = 0.0f; by[k] = 0.0f; }
            #pragma unroll
            for (int k = 0; k < 4; k++) { ax[k] = s_px[n][k]; ay[k] = s_py[n][k]; }

            int cnt = 4;
            cnt = clip_stage<4, 5>( 1.0f,  0.0f, -x0, ax, ay, bx, by, cnt);
            cnt = clip_stage<5, 6>(-1.0f,  0.0f,  x1, bx, by, ax, ay, cnt);
            cnt = clip_stage<6, 7>( 0.0f,  1.0f, -y0, ax, ay, bx, by, cnt);
            cnt = clip_stage<7, 8>( 0.0f, -1.0f,  y1, bx, by, ax, ay, cnt);

            // shoelace area of clipped polygon (all indices constant)
            float sum = 0.0f;
            #pragma unroll
            for (int e = 0; e < 8; e++) {
                const bool valid = (e < cnt);
                const float nx = (e + 1 < 8 && e + 1 < cnt) ? ax[e + 1] : ax[0];
                const float ny = (e + 1 < 8 && e + 1 < cnt) ? ay[e + 1] : ay[0];
                const float cr = ax[e] * ny - nx * ay[e];
                sum += valid ? cr : 0.0f;
            }
            const float area = 0.5f * fabsf(sum);

            inter = area * zov;
            const float box_vol = s_qa[n] * (zb1 - zb0);
            iou = inter / (vox_vol + box_vol - inter + 1e-9f);
        }

        if (iou > best_iou) {   // strict > => first-max, matches jnp.argmax
            best_iou   = iou;
            best_inter = inter;
            best_idx   = n;
        }
    }

    const bool mask = best_inter > 0.5f * vox_vol;
    const float o0 = mask ? s_sin[best_idx] : 0.0f;
    const float o1 = mask ? s_cos[best_idx] : 0.0f;

    const size_t oidx = ((size_t)b * NVOX + v) * 2;
    out[oidx]     = o0;
    out[oidx + 1] = o1;
}

extern "C" void kernel_launch(void* const* d_in, const int* in_sizes, int n_in,
                              void* d_out, int out_size, void* d_ws, size_t ws_size,
                              hipStream_t stream) {
    const float* corners = (const float*)d_in[0];   // (4,16,8,3) fp32
    const float* vsizes  = (const float*)d_in[1];   // (4,3) fp32
    float* out = (float*)d_out;                     // (4*32768, 2) fp32

    const int B = 4;
    dim3 grid(B * BLOCKS_PER_BATCH);  // 512 blocks
    dim3 block(256);
    box3d_encoder_kernel<<<grid, block, 0, stream>>>(corners, vsizes, out);
}

// Round 3
// 83.278 us; speedup vs baseline: 1.0417x; 1.0311x over previous
//
#include <hip/hip_runtime.h>
#include <math.h>

#define NBOX 16
#define GX 64
#define GY 64
#define GZ 8
#define NVOX (GX * GY * GZ)            // 32768
#define BLK 64
#define BLOCKS_PER_BATCH (NVOX / BLK)  // 512

// ---------------------------------------------------------------------------
// Fully scalar (no arrays -> no alloca -> no scratch) Sutherland-Hodgman clip.
// Vertex buffers are named registers i0x..i7y (input) / q0x..q7y (output).
// The dynamic append becomes an explicit v_cndmask select chain over slots.
// Emission order per edge (intersection point, then next-vertex) matches the
// reference's stable argsort compaction bit-exactly.
// ---------------------------------------------------------------------------

#define EMIT_SLOT(K, PX, PY) \
    q##K##x = (_c && oc == K) ? (PX) : q##K##x; \
    q##K##y = (_c && oc == K) ? (PY) : q##K##y;

#define EMIT8C(COND, PX, PY) do { const bool _c = (COND); \
    EMIT_SLOT(0, PX, PY) EMIT_SLOT(1, PX, PY) EMIT_SLOT(2, PX, PY) \
    EMIT_SLOT(3, PX, PY) EMIT_SLOT(4, PX, PY) EMIT_SLOT(5, PX, PY) \
    EMIT_SLOT(6, PX, PY) EMIT_SLOT(7, PX, PY) \
    oc += _c ? 1 : 0; } while (0)

// One SH edge step: cur = vertex E, next = (E+1<cnt) ? vertex NE : vertex 0.
// All garbage values (E >= cnt) are gated out by _cv before emission.
#define CLIP_EDGE(E, NE) do { \
    const bool  _cv = (E) < cnt; \
    const bool  _wr = !((E) + 1 < cnt); \
    const float _cx = i##E##x, _cy = i##E##y; \
    const float _nx = _wr ? i0x : i##NE##x; \
    const float _ny = _wr ? i0y : i##NE##y; \
    const float _dc = pa * _cx + pb * _cy + pc; \
    const float _dn = pa * _nx + pb * _ny + pc; \
    float _dm = _dc - _dn; \
    _dm = (fabsf(_dm) < 1e-12f) ? 1.0f : _dm; \
    const float _tt  = _dc / _dm; \
    const float _ipx = _cx + _tt * (_nx - _cx); \
    const float _ipy = _cy + _tt * (_ny - _cy); \
    { const bool _e1 = _cv && ((_dc >= 0.0f) != (_dn >= 0.0f)); EMIT8C(_e1, _ipx, _ipy); } \
    { const bool _e2 = _cv && (_dn >= 0.0f);                    EMIT8C(_e2, _nx, _ny); } \
} while (0)

#define STAGE_DECL_Q() \
    float q0x = 0.0f, q0y = 0.0f, q1x = 0.0f, q1y = 0.0f, \
          q2x = 0.0f, q2y = 0.0f, q3x = 0.0f, q3y = 0.0f, \
          q4x = 0.0f, q4y = 0.0f, q5x = 0.0f, q5y = 0.0f, \
          q6x = 0.0f, q6y = 0.0f, q7x = 0.0f, q7y = 0.0f; \
    int oc = 0;

#define COPY_Q_TO_I() \
    i0x = q0x; i0y = q0y; i1x = q1x; i1y = q1y; \
    i2x = q2x; i2y = q2y; i3x = q3x; i3y = q3y; \
    i4x = q4x; i4y = q4y; i5x = q5x; i5y = q5y; \
    i6x = q6x; i6y = q6y; i7x = q7x; i7y = q7y; \
    cnt = oc;

#define SHOE(E, NE) { \
    const bool  _v  = (E) < cnt; \
    const bool  _wr = !((E) + 1 < cnt); \
    const float _nx = _wr ? i0x : i##NE##x; \
    const float _ny = _wr ? i0y : i##NE##y; \
    const float _cr = i##E##x * _ny - _nx * i##E##y; \
    ssum += _v ? _cr : 0.0f; }

// One thread per voxel. Block = 64 threads (one wave); 512 blocks per batch.
__global__ __launch_bounds__(BLK, 4) void box3d_encoder_kernel(
    const float* __restrict__ corners,   // (B, 16, 8, 3)
    const float* __restrict__ vsizes,    // (B, 3) -- reference uses row 0 only
    float* __restrict__ out)             // (B*NVOX, 2)
{
    __shared__ float s_px[NBOX][4], s_py[NBOX][4];
    __shared__ float s_zb0[NBOX], s_zb1[NBOX], s_qa[NBOX];
    __shared__ float s_sin[NBOX], s_cos[NBOX];
    __shared__ float s_ax0[NBOX], s_ax1[NBOX], s_ay0[NBOX], s_ay1[NBOX];

    const int b     = blockIdx.x >> 9;              // / BLOCKS_PER_BATCH
    const int vbase = (blockIdx.x & (BLOCKS_PER_BATCH - 1)) << 6;
    const int t     = threadIdx.x;

    const float vs0 = vsizes[0], vs1 = vsizes[1], vs2 = vsizes[2];
    const float vox_vol = vs0 * vs1 * vs2;

    if (t < NBOX) {
        const float* c8 = corners + ((size_t)b * NBOX + t) * 8 * 3;
        float px[4], py[4];
        float zmin = c8[2], zmax = c8[2];
        #pragma unroll
        for (int k = 0; k < 8; k++) {
            float z = c8[k * 3 + 2];
            zmin = fminf(zmin, z);
            zmax = fmaxf(zmax, z);
        }
        #pragma unroll
        for (int k = 0; k < 4; k++) { px[k] = c8[k * 3 + 0]; py[k] = c8[k * 3 + 1]; }

        float sum = 0.0f;
        #pragma unroll
        for (int k = 0; k < 4; k++) {
            int n = (k + 1) & 3;
            sum += px[k] * py[n] - px[n] * py[k];
        }
        s_qa[t] = 0.5f * fabsf(sum);

        float h = atan2f(py[0] - py[3], px[0] - px[3]);
        s_sin[t] = sinf(h);
        s_cos[t] = cosf(h);

        s_zb0[t] = zmin;
        s_zb1[t] = zmax;

        float ax0 = px[0], ax1 = px[0], ay0 = py[0], ay1 = py[0];
        #pragma unroll
        for (int k = 1; k < 4; k++) {
            ax0 = fminf(ax0, px[k]); ax1 = fmaxf(ax1, px[k]);
            ay0 = fminf(ay0, py[k]); ay1 = fmaxf(ay1, py[k]);
        }
        s_ax0[t] = ax0; s_ax1[t] = ax1; s_ay0[t] = ay0; s_ay1[t] = ay1;

        #pragma unroll
        for (int k = 0; k < 4; k++) { s_px[t][k] = px[k]; s_py[t][k] = py[k]; }
    }
    __syncthreads();

    // voxel indices: v = i*512 + j*8 + k ; wave covers 8j x 8k, single i
    const int v  = vbase + t;
    const int iz = v & 7;
    const int iy = (v >> 3) & 63;
    const int ix = v >> 9;
    const float fi = (float)(ix - 32);
    const float fj = (float)(iy - 32);
    const float fk = (float)(iz - 4);
    const float x0 = fi * vs0, x1 = (fi + 1.0f) * vs0;
    const float y0 = fj * vs1, y1 = (fj + 1.0f) * vs1;
    const float z0 = fk * vs2, z1 = (fk + 1.0f) * vs2;

    float best_iou   = -1.0f;
    float best_inter = 0.0f;
    int   best_idx   = 0;

    #pragma unroll 1
    for (int n = 0; n < NBOX; n++) {
        float iou = 0.0f, inter = 0.0f;

        const float zb0 = s_zb0[n], zb1 = s_zb1[n];
        const float zov_raw = fminf(z1, zb1) - fmaxf(z0, zb0);
        const bool overlap = (zov_raw > 0.0f)
                          && (s_ax0[n] < x1) && (s_ax1[n] > x0)
                          && (s_ay0[n] < y1) && (s_ay1[n] > y0);

        // Wave-uniform gate: whole wave skips when no lane overlaps box n.
        // Inside, all lanes compute the full reference formula (clip area is
        // exactly 0 and zov clamps to 0 for non-overlapping lanes).
        if (__any((int)overlap)) {
            float i0x = s_px[n][0], i0y = s_py[n][0];
            float i1x = s_px[n][1], i1y = s_py[n][1];
            float i2x = s_px[n][2], i2y = s_py[n][2];
            float i3x = s_px[n][3], i3y = s_py[n][3];
            float i4x = 0.0f, i4y = 0.0f, i5x = 0.0f, i5y = 0.0f;
            float i6x = 0.0f, i6y = 0.0f, i7x = 0.0f, i7y = 0.0f;
            int cnt = 4;

            {   // plane x >= x0 : 4 -> <=5
                const float pa = 1.0f, pb = 0.0f, pc = -x0;
                STAGE_DECL_Q();
                CLIP_EDGE(0, 1); CLIP_EDGE(1, 2); CLIP_EDGE(2, 3); CLIP_EDGE(3, 4);
                COPY_Q_TO_I();
            }
            {   // plane x <= x1 : <=5 -> <=6
                const float pa = -1.0f, pb = 0.0f, pc = x1;
                STAGE_DECL_Q();
                CLIP_EDGE(0, 1); CLIP_EDGE(1, 2); CLIP_EDGE(2, 3); CLIP_EDGE(3, 4);
                CLIP_EDGE(4, 5);
                COPY_Q_TO_I();
            }
            {   // plane y >= y0 : <=6 -> <=7
                const float pa = 0.0f, pb = 1.0f, pc = -y0;
                STAGE_DECL_Q();
                CLIP_EDGE(0, 1); CLIP_EDGE(1, 2); CLIP_EDGE(2, 3); CLIP_EDGE(3, 4);
                CLIP_EDGE(4, 5); CLIP_EDGE(5, 6);
                COPY_Q_TO_I();
            }
            {   // plane y <= y1 : <=7 -> <=8
                const float pa = 0.0f, pb = -1.0f, pc = y1;
                STAGE_DECL_Q();
                CLIP_EDGE(0, 1); CLIP_EDGE(1, 2); CLIP_EDGE(2, 3); CLIP_EDGE(3, 4);
                CLIP_EDGE(4, 5); CLIP_EDGE(5, 6); CLIP_EDGE(6, 7);
                COPY_Q_TO_I();
            }

            float ssum = 0.0f;
            SHOE(0, 1) SHOE(1, 2) SHOE(2, 3) SHOE(3, 4)
            SHOE(4, 5) SHOE(5, 6) SHOE(6, 7) SHOE(7, 7)
            const float area = 0.5f * fabsf(ssum);

            const float zov = fmaxf(zov_raw, 0.0f);
            inter = area * zov;
            const float box_vol = s_qa[n] * (zb1 - zb0);
            iou = inter / (vox_vol + box_vol - inter + 1e-9f);
        }

        if (iou > best_iou) {   // strict > => first-max, matches jnp.argmax
            best_iou   = iou;
            best_inter = inter;
            best_idx   = n;
        }
    }

    const bool mask = best_inter > 0.5f * vox_vol;
    float2 o;
    o.x = mask ? s_sin[best_idx] : 0.0f;
    o.y = mask ? s_cos[best_idx] : 0.0f;
    reinterpret_cast<float2*>(out)[(size_t)b * NVOX + v] = o;
}

extern "C" void kernel_launch(void* const* d_in, const int* in_sizes, int n_in,
                              void* d_out, int out_size, void* d_ws, size_t ws_size,
                              hipStream_t stream) {
    const float* corners = (const float*)d_in[0];   // (4,16,8,3) fp32
    const float* vsizes  = (const float*)d_in[1];   // (4,3) fp32
    float* out = (float*)d_out;                     // (4*32768, 2) fp32

    const int B = 4;
    dim3 grid(B * BLOCKS_PER_BATCH);  // 2048 blocks
    dim3 block(BLK);                  // 64 threads = 1 wave
    box3d_encoder_kernel<<<grid, block, 0, stream>>>(corners, vsizes, out);
}